// Round 3
// baseline (244.131 us; speedup 1.0000x reference)
//
#include <hip/hip_runtime.h>
#include <hip/hip_bf16.h>

// ---------------------------------------------------------------------------
// GNNBase: B=512, N=32, F=16, H=128, E=16, NE=3, L=2, D0=32
// 3-kernel pipeline:
//   k_prep : bf16 xj table [16384][32] + k-PERMUTED bf16 W^T images + zero bins
//   k_pair : 512 thr (8 waves, 16-row C-tiles), per (b, 4 c's):
//            3 MFMA layers w/ bias-in-acc + fused LN, split-K weight staging,
//            masked aggregate -> h (f32, LDS) -> fused score/exp/atomic-bins,
//            hsel (agent rows) + exp_s agent scalar
//   k_final: 512 agent rows: alpha = exp_s/sum(bins); fc3/ln3/fc4/ln4 -> out
//
// k-permutation: epilogue C-frag cols pair naturally as (32s+li, 32s+16+li);
// we store that pair as one u32 at chunk position 2*li (2-way bank = free).
// The SAME within-chunk permutation pi(p) = p&1 ? 16+(p>>1) : (p>>1) is baked
// into the hidden-layer weight k-order in k_prep, so A.B dot products align.
// ---------------------------------------------------------------------------

typedef __attribute__((ext_vector_type(8))) __bf16 bf16x8;
typedef __attribute__((ext_vector_type(4))) float  f32x4;

__device__ __forceinline__ unsigned short f2bf(float f) {
  union { float f; unsigned u; } v; v.f = f;
  unsigned u = v.u;
  u += 0x7FFFu + ((u >> 16) & 1u);   // RTNE
  return (unsigned short)(u >> 16);
}

__device__ __forceinline__ unsigned pk2bf(float a, float b) {
  union { __hip_bfloat162 h; unsigned u; } cv;
  cv.h = __float22bfloat162_rn(make_float2(a, b));   // .x -> low 16
  return cv.u;
}

__device__ __forceinline__ bf16x8 lds_frag(const unsigned short* p) {
  union { uint4 u; bf16x8 v; } x;
  x.u = *(const uint4*)p;            // ds_read_b128
  return x.v;
}

__device__ __forceinline__ f32x4 mfma16(bf16x8 a, bf16x8 b, f32x4 c) {
  return __builtin_amdgcn_mfma_f32_16x16x32_bf16(a, b, c, 0, 0, 0);
}

// async global->LDS, 16 B per lane. LDS dest = wave-uniform base + lane*16.
__device__ __forceinline__ void gll16(const void* g, void* l) {
  __builtin_amdgcn_global_load_lds(
      (const __attribute__((address_space(1))) unsigned int*)(unsigned long long)g,
      (__attribute__((address_space(3))) unsigned int*)(unsigned int)(unsigned long long)l,
      16, 0, 0);
}

// stage a contiguous 18432-B weight image into LDS (512 threads)
__device__ __forceinline__ void stage18432(const char* g, char* l, int tid) {
  int off = tid * 16;
  gll16(g + off, l + off);
  gll16(g + off + 8192, l + off + 8192);
  if (tid < 128) gll16(g + off + 16384, l + off + 16384);
}

// ---------------------------------------------------------------------------
// workspace layout (bytes)
// ---------------------------------------------------------------------------
#define WS_HSEL  0           // f32 h agent rows [512][128]     262144
#define WS_SWS   262144      // f32 exp(s_agent) [512]            2048
#define WS_BINS  264192      // f32 partial exp-sums [64]          256
#define WS_XJB   264448      // bf16 xj [16384][32]            1048576
#define WS_WT0P  1313024     // bf16 lin1 W^T [128][40]          10240
#define WS_W1P   1323264     // bf16 linh0 W^T [2h][128][72]     36864
#define WS_W2P   1360128     // bf16 linh1 W^T [2h][128][72]     36864

// ---------------------------------------------------------------------------
// k_prep
// ---------------------------------------------------------------------------
#define PREP_N0 524288                 // xjb elements
#define PREP_N1 (PREP_N0 + 5120)      // + WT0p [128][40] (natural k)
#define PREP_N2 (PREP_N1 + 36864)     // + W1p/W2p (permuted k)
#define PREP_N3 (PREP_N2 + 64)        // + bins zero

__global__ void k_prep(const float* __restrict__ node_obs, const float* __restrict__ ent_emb,
                       const float* __restrict__ lin1_w, const float* __restrict__ linh_w,
                       char* __restrict__ ws) {
  int idx = blockIdx.x * 256 + threadIdx.x;
  unsigned short* xjb  = (unsigned short*)(ws + WS_XJB);
  unsigned short* WT0p = (unsigned short*)(ws + WS_WT0P);
  unsigned short* W1p  = (unsigned short*)(ws + WS_W1P);
  unsigned short* W2p  = (unsigned short*)(ws + WS_W2P);
  if (idx < PREP_N0) {
    int row = idx >> 5, k = idx & 31;
    float val;
    if (k < 15) val = node_obs[row * 16 + k];
    else if (k < 31) {
      int ent = (int)node_obs[row * 16 + 15];
      val = ent_emb[ent * 16 + (k - 15)];
    } else val = 0.f;   // e slot, patched per-wave in k_pair
    xjb[idx] = f2bf(val);
  } else if (idx < PREP_N1) {
    int r = idx - PREP_N0;
    int n = r / 40, kk = r - n * 40;
    WT0p[n * 40 + kk] = (kk < 32) ? f2bf(lin1_w[kk * 128 + n]) : (unsigned short)0;
  } else if (idx < PREP_N2) {
    int r = idx - PREP_N1;
    int l = r / 18432; r -= l * 18432;
    int h = r / 9216;  r -= h * 9216;
    int n = r / 72;    int kk = r - n * 72;
    unsigned short v = 0;
    if (kk < 64) {
      int p = kk & 31, chunk = kk >> 5;
      int sk = (p & 1) ? (16 + (p >> 1)) : (p >> 1);   // pi(p)
      int k = h * 64 + chunk * 32 + sk;
      v = f2bf(linh_w[l * 16384 + k * 128 + n]);
    }
    (l ? W2p : W1p)[h * 9216 + n * 72 + kk] = v;
  } else if (idx < PREP_N3) {
    ((float*)(ws + WS_BINS))[idx - PREP_N2] = 0.f;
  }
}

// ---------------------------------------------------------------------------
// k_pair helpers. C-frag (16x16x32): col = tj*16+(lane&15), row = quad*4+reg.
// ---------------------------------------------------------------------------
__device__ __forceinline__ void init_acc(f32x4 (&acc)[8], const float* __restrict__ gbias,
                                         int li) {
#pragma unroll
  for (int tj = 0; tj < 8; ++tj) {
    float bv = gbias[tj * 16 + li];
    acc[tj] = (f32x4){bv, bv, bv, bv};
  }
}

__device__ __forceinline__ void mfma_half2(f32x4 (&acc)[8],
    const unsigned short* Xs, const unsigned short* Wh,
    int rowbase, int koff, int li, int quad) {
#pragma unroll
  for (int s = 0; s < 2; ++s) {
    bf16x8 a = lds_frag(Xs + (rowbase + li) * 136 + koff + s * 32 + quad * 8);
#pragma unroll
    for (int tj = 0; tj < 8; ++tj) {
      bf16x8 bb = lds_frag(Wh + (tj * 16 + li) * 72 + s * 32 + quad * 8);
      acc[tj] = mfma16(a, bb, acc[tj]);
    }
  }
}

// bias already in acc. relu + LN, write k-permuted u32 pairs.
__device__ __forceinline__ void epilogue_store(f32x4 (&acc)[8],
    const float* __restrict__ gg, const float* __restrict__ gbe,
    unsigned short* Xs, int rowbase, int li, int quad) {
  float g[8], be[8];
#pragma unroll
  for (int tj = 0; tj < 8; ++tj) { g[tj] = gg[tj * 16 + li]; be[tj] = gbe[tj * 16 + li]; }
#pragma unroll
  for (int rg = 0; rg < 4; ++rg) {
    float v[8], s1 = 0.f, s2 = 0.f;
#pragma unroll
    for (int tj = 0; tj < 8; ++tj) {
      float x = fmaxf(acc[tj][rg], 0.f);
      v[tj] = x; s1 += x; s2 = fmaf(x, x, s2);
    }
#pragma unroll
    for (int m = 1; m < 16; m <<= 1) { s1 += __shfl_xor(s1, m); s2 += __shfl_xor(s2, m); }
    float mean = s1 * 0.0078125f;
    float var  = fmaf(s2, 0.0078125f, -mean * mean);
    float inv  = rsqrtf(var + 1e-5f);
    int row = rowbase + quad * 4 + rg;
    unsigned short* xr = Xs + row * 136;
    float o[8];
#pragma unroll
    for (int tj = 0; tj < 8; ++tj) o[tj] = fmaf((v[tj] - mean) * inv, g[tj], be[tj]);
#pragma unroll
    for (int tjp = 0; tjp < 4; ++tjp) {
      unsigned u = pk2bf(o[2 * tjp], o[2 * tjp + 1]);   // cols (32t+li, 32t+16+li)
      *(unsigned*)(xr + tjp * 32 + 2 * li) = u;         // pos 2li / 2li+1 (pi)
    }
  }
}

// final layer: LN + masked partial col-sum over this wave's 16 rows -> scratch.
__device__ __forceinline__ void epilogue_agg(f32x4 (&acc)[8],
    const float* __restrict__ gg, const float* __restrict__ gbe,
    float mflag, char* smem, int rowbase, int li, int quad) {
  float g[8], be[8], cs[8];
#pragma unroll
  for (int tj = 0; tj < 8; ++tj) {
    g[tj] = gg[tj * 16 + li]; be[tj] = gbe[tj * 16 + li]; cs[tj] = 0.f;
  }
#pragma unroll
  for (int rg = 0; rg < 4; ++rg) {
    float v[8], s1 = 0.f, s2 = 0.f;
#pragma unroll
    for (int tj = 0; tj < 8; ++tj) {
      float x = fmaxf(acc[tj][rg], 0.f);
      v[tj] = x; s1 += x; s2 = fmaf(x, x, s2);
    }
#pragma unroll
    for (int m = 1; m < 16; m <<= 1) { s1 += __shfl_xor(s1, m); s2 += __shfl_xor(s2, m); }
    float mean = s1 * 0.0078125f;
    float var  = fmaf(s2, 0.0078125f, -mean * mean);
    float inv  = rsqrtf(var + 1e-5f);
    int rl = quad * 4 + rg;
    float mk = __shfl(mflag, rl);   // mask for this wave's local row rl
#pragma unroll
    for (int tj = 0; tj < 8; ++tj)
      cs[tj] = fmaf(mk, fmaf((v[tj] - mean) * inv, g[tj], be[tj]), cs[tj]);
  }
#pragma unroll
  for (int tj = 0; tj < 8; ++tj) {
    cs[tj] += __shfl_xor(cs[tj], 16);
    cs[tj] += __shfl_xor(cs[tj], 32);
  }
  if (quad == 0) {
    float* scr = (float*)(smem + rowbase * 272);   // own Xs rows as f32 scratch
#pragma unroll
    for (int tj = 0; tj < 8; ++tj) scr[tj * 16 + li] = cs[tj];
  }
}

// ---------------------------------------------------------------------------
// k_pair: block = (b, c0..c0+3), 8 waves: wave (cl = wv&3, hf = wv>>2) owns a
// 16x128 C-tile (rows = pair rows hf*16..+15 of column c0+cl).
// LDS: Xs [128][136] bf16 (34816, overlaid by 4 xj tiles in phase 0, then by
// f32 h-scratch after the last MFMA) + Wh [128][72] bf16 (18432) = 53248 B
// -> 3 blocks/CU = 24 waves/CU.
// ---------------------------------------------------------------------------
#define SMP_W 34816
#define SMP_TOTAL 53248

__global__ __launch_bounds__(512, 6)
void k_pair(const float* __restrict__ adj, const int* __restrict__ agent_id,
            const float* __restrict__ lin1_b, const float* __restrict__ ln1_g,
            const float* __restrict__ ln1_beta,
            const float* __restrict__ linh_b, const float* __restrict__ lnh_g,
            const float* __restrict__ lnh_b,
            const float* __restrict__ fc2a_w, const float* __restrict__ fc2a_b,
            const float* __restrict__ fc2b_w, const float* __restrict__ fc2b_b,
            char* __restrict__ ws) {
  __shared__ alignas(16) char smem[SMP_TOTAL];
  unsigned short* Xs = (unsigned short*)smem;
  unsigned short* Wh = (unsigned short*)(smem + SMP_W);

  const unsigned short* xjb = (const unsigned short*)(ws + WS_XJB);
  const char* WT0p = ws + WS_WT0P;
  const char* W1p  = ws + WS_W1P;
  const char* W2p  = ws + WS_W2P;

  const int tid  = threadIdx.x;
  const int b    = blockIdx.x >> 3;
  const int c0   = (blockIdx.x & 7) << 2;
  const int lane = tid & 63, li = lane & 15, quad = lane >> 4, wv = tid >> 6;
  const int cl = wv & 3, hf = wv >> 2;
  const int rowbase = cl * 32 + hf * 16;
  const int cglob   = c0 + cl;
  const int agent   = agent_id[b];

  // ---- phase 0: xj tiles (stride 40, per c) + WT0p + e-patch/mask ----
  {
    const uint4* src = (const uint4*)xjb;
    char* tile = smem + cl * 2560;
    int r = lane >> 2, p = lane & 3;
    uint4 v = src[(b * 32 + hf * 16 + r) * 4 + p];
    *(uint4*)(tile + (hf * 16 + r) * 80 + p * 16) = v;
  }
  {
    int off = tid * 16;
    gll16(WT0p + off, smem + SMP_W + off);
    if (tid < 128) gll16(WT0p + off + 8192, smem + SMP_W + off + 8192);
  }
  float mflag = 0.f;
  if (lane < 16) {
    int r = hf * 16 + lane;
    float a = adj[(b * 32 + r) * 32 + cglob];
    float e = (a > 0.f && a < 1.f) ? a : 0.f;
    mflag = (e != 0.f) ? 1.f : 0.f;
    ((unsigned short*)(smem + cl * 2560 + r * 80))[31] = f2bf(e);
  }
  __syncthreads();                                   // (1)

  f32x4 acc[8];

  // ---- layer 0 ----
  init_acc(acc, lin1_b, li);
  {
    const unsigned short* xt = (const unsigned short*)(smem + cl * 2560);
    bf16x8 a0 = lds_frag(xt + (hf * 16 + li) * 40 + quad * 8);
#pragma unroll
    for (int tj = 0; tj < 8; ++tj) {
      bf16x8 bb = lds_frag(Wh + (tj * 16 + li) * 40 + quad * 8);
      acc[tj] = mfma16(a0, bb, acc[tj]);
    }
  }
  __syncthreads();                                   // (2) tiles+Wh read done
  stage18432(W1p, smem + SMP_W, tid);                // W1 half0 in flight
  epilogue_store(acc, ln1_g, ln1_beta, Xs, rowbase, li, quad);
  __syncthreads();                                   // (3)

  // ---- hidden layer 1 ----
  init_acc(acc, linh_b, li);
  mfma_half2(acc, Xs, Wh, rowbase, 0, li, quad);
  __syncthreads();                                   // (4)
  stage18432(W1p + 18432, smem + SMP_W, tid);
  __syncthreads();                                   // (5)
  mfma_half2(acc, Xs, Wh, rowbase, 64, li, quad);
  __syncthreads();                                   // (6)
  stage18432(W2p, smem + SMP_W, tid);
  epilogue_store(acc, lnh_g, lnh_b, Xs, rowbase, li, quad);   // own rows only
  __syncthreads();                                   // (7)

  // ---- hidden layer 2 + masked aggregate ----
  init_acc(acc, linh_b + 128, li);
  mfma_half2(acc, Xs, Wh, rowbase, 0, li, quad);
  __syncthreads();                                   // (8)
  stage18432(W2p + 18432, smem + SMP_W, tid);
  __syncthreads();                                   // (9)
  mfma_half2(acc, Xs, Wh, rowbase, 64, li, quad);
  epilogue_agg(acc, lnh_g + 128, lnh_b + 128, mflag, smem, rowbase, li, quad);
  __syncthreads();                                   // (10) scratch ready, Wh free

  // ---- combine wave-pair partials -> h (f32) + hsel ----
  float* hbuf = (float*)(smem + SMP_W);
  float* pbuf = hbuf + 512;
  {
    int c = tid >> 7, col = tid & 127;
    const float* sA = (const float*)(smem + (c * 32) * 272);
    const float* sB = (const float*)(smem + (c * 32 + 16) * 272);
    float h = sA[col] + sB[col];
    hbuf[c * 128 + col] = h;
    if (c0 + c == agent) ((float*)(ws + WS_HSEL))[b * 128 + col] = h;
  }
  __syncthreads();                                   // (11)

  // ---- fused score: u = relu(h@fc2a + b); s = u@fc2b + b2; exp -> bins ----
  {
    int cs_ = wv >> 1, col = (wv & 1) * 64 + lane;
    const float4* hr = (const float4*)(hbuf + cs_ * 128);
    float t0 = fc2a_b[col], t1 = 0.f, t2 = 0.f, t3 = 0.f;
#pragma unroll
    for (int k4 = 0; k4 < 32; ++k4) {
      float4 hv = hr[k4];
      t0 = fmaf(hv.x, fc2a_w[(k4 * 4 + 0) * 128 + col], t0);
      t1 = fmaf(hv.y, fc2a_w[(k4 * 4 + 1) * 128 + col], t1);
      t2 = fmaf(hv.z, fc2a_w[(k4 * 4 + 2) * 128 + col], t2);
      t3 = fmaf(hv.w, fc2a_w[(k4 * 4 + 3) * 128 + col], t3);
    }
    float t = (t0 + t1) + (t2 + t3);
    t = fmaxf(t, 0.f) * fc2b_w[col];
#pragma unroll
    for (int m = 1; m < 64; m <<= 1) t += __shfl_xor(t, m);
    if (lane == 0) pbuf[wv] = t;
  }
  __syncthreads();                                   // (12)
  if (tid < 4) {
    float s = pbuf[2 * tid] + pbuf[2 * tid + 1] + fc2b_b[0];
    float e = __expf(s);
    if (c0 + tid == agent) ((float*)(ws + WS_SWS))[b] = e;
    atomicAdd((float*)(ws + WS_BINS) + (b & 63), e);
  }
}

// ---------------------------------------------------------------------------
// k_final: 512 agent rows. alpha = exp_s[b] / sum(bins).
// ---------------------------------------------------------------------------
__global__ __launch_bounds__(128)
void k_final(const char* __restrict__ ws,
             const float* __restrict__ fc3_w, const float* __restrict__ fc3_b,
             const float* __restrict__ ln3_g, const float* __restrict__ ln3_b,
             const float* __restrict__ fc4_w, const float* __restrict__ fc4_b,
             const float* __restrict__ ln4_g, const float* __restrict__ ln4_b,
             float* __restrict__ out) {
  const float* hsel = (const float*)(ws + WS_HSEL);
  const float* sws  = (const float*)(ws + WS_SWS);
  const float* bins = (const float*)(ws + WS_BINS);
  __shared__ float xrow[128];
  __shared__ float red[8];
  const int tid = threadIdx.x;
  const int b = blockIdx.x;

  float bsum = bins[tid & 63];
#pragma unroll
  for (int m = 1; m < 64; m <<= 1) bsum += __shfl_xor(bsum, m);
  float alpha = sws[b] / bsum;

  xrow[tid] = hsel[b * 128 + tid];
  __syncthreads();
  float t = fc3_b[tid];
  for (int k = 0; k < 128; ++k) t = fmaf(xrow[k], fc3_w[k * 128 + tid], t);
  t = fmaxf(t, 0.f);
  float s1 = t, s2 = t * t;
#pragma unroll
  for (int m = 1; m < 64; m <<= 1) { s1 += __shfl_xor(s1, m); s2 += __shfl_xor(s2, m); }
  if ((tid & 63) == 0) { red[(tid >> 6) * 2] = s1; red[(tid >> 6) * 2 + 1] = s2; }
  __syncthreads();
  s1 = red[0] + red[2]; s2 = red[1] + red[3];
  float mean = s1 * 0.0078125f;
  float var  = s2 * 0.0078125f - mean * mean;
  float inv  = rsqrtf(var + 1e-5f);
  float v = (t - mean) * inv * ln3_g[tid] + ln3_b[tid];
  __syncthreads();
  xrow[tid] = alpha * v;
  __syncthreads();
  float x = fc4_b[tid];
  for (int k = 0; k < 128; ++k) x = fmaf(xrow[k], fc4_w[k * 128 + tid], x);
  x = fmaxf(x, 0.f);
  s1 = x; s2 = x * x;
#pragma unroll
  for (int m = 1; m < 64; m <<= 1) { s1 += __shfl_xor(s1, m); s2 += __shfl_xor(s2, m); }
  if ((tid & 63) == 0) { red[4 + (tid >> 6) * 2] = s1; red[5 + (tid >> 6) * 2] = s2; }
  __syncthreads();
  s1 = red[4] + red[6]; s2 = red[5] + red[7];
  mean = s1 * 0.0078125f;
  var  = s2 * 0.0078125f - mean * mean;
  inv  = rsqrtf(var + 1e-5f);
  out[b * 128 + tid] = (x - mean) * inv * ln4_g[tid] + ln4_b[tid];
}

// ---------------------------------------------------------------------------
extern "C" void kernel_launch(void* const* d_in, const int* in_sizes, int n_in,
                              void* d_out, int out_size, void* d_ws, size_t ws_size,
                              hipStream_t stream) {
  (void)in_sizes; (void)n_in; (void)out_size; (void)ws_size;
  const float* node_obs = (const float*)d_in[0];
  const float* adj      = (const float*)d_in[1];
  const int*   agent_id = (const int*)d_in[2];
  const float* ent_emb  = (const float*)d_in[3];
  const float* lin1_w   = (const float*)d_in[4];
  const float* lin1_b   = (const float*)d_in[5];
  const float* ln1_g    = (const float*)d_in[6];
  const float* ln1_beta = (const float*)d_in[7];
  const float* linh_w   = (const float*)d_in[8];
  const float* linh_b   = (const float*)d_in[9];
  const float* lnh_g    = (const float*)d_in[10];
  const float* lnh_b    = (const float*)d_in[11];
  const float* fc2a_w   = (const float*)d_in[12];
  const float* fc2a_b   = (const float*)d_in[13];
  const float* fc2b_w   = (const float*)d_in[14];
  const float* fc2b_b   = (const float*)d_in[15];
  const float* fc3_w    = (const float*)d_in[16];
  const float* fc3_b    = (const float*)d_in[17];
  const float* ln3_g    = (const float*)d_in[18];
  const float* ln3_b    = (const float*)d_in[19];
  const float* fc4_w    = (const float*)d_in[20];
  const float* fc4_b    = (const float*)d_in[21];
  const float* ln4_g    = (const float*)d_in[22];
  const float* ln4_b    = (const float*)d_in[23];
  float* out = (float*)d_out;
  char* ws = (char*)d_ws;

  k_prep<<<(PREP_N3 + 255) / 256, 256, 0, stream>>>(node_obs, ent_emb, lin1_w, linh_w, ws);
  k_pair<<<4096, 512, 0, stream>>>(adj, agent_id, lin1_b, ln1_g, ln1_beta,
                                   linh_b, lnh_g, lnh_b,
                                   fc2a_w, fc2a_b, fc2b_w, fc2b_b, ws);
  k_final<<<512, 128, 0, stream>>>(ws, fc3_w, fc3_b, ln3_g, ln3_b,
                                   fc4_w, fc4_b, ln4_g, ln4_b, out);
}